// Round 2
// baseline (832.914 us; speedup 1.0000x reference)
//
#include <hip/hip_runtime.h>
#include <math.h>

// B=32, S=32, LQ=30, LS=40, D=300, F=256, FS=3, K=5
// out layout: [0]=total_loss, [1..1024]=sent_output(B,S), [1025..1056]=doc_em(B)

__global__ __launch_bounds__(256) void k_transpose_filters(const float* __restrict__ filters,
                                                           float* __restrict__ fT) {
  int kd = blockIdx.x;   // 0..899  (k*300+d)
  int f  = threadIdx.x;  // 0..255
  fT[kd * 256 + f] = filters[f * 900 + kd];
}

// One block per sequence. out[j,f] = sum_{k=0..2} x[j+k] . W[f,k,:], zero past row L-1.
template<int L, int RT>
__global__ __launch_bounds__(256) void k_conv(const int* __restrict__ tokens,
                                              const float* __restrict__ embeds,
                                              const float* __restrict__ fT,
                                              float* __restrict__ out) {
  constexpr int ROWS = RT * 4 + 2;
  __shared__ float xs[ROWS * 300];
  const int seq = blockIdx.x;
  const int tid = threadIdx.x;
  const int* tok = tokens + (size_t)seq * L;
  for (int r = 0; r < L; ++r) {
    const float* src = embeds + (size_t)tok[r] * 300;
    for (int d = tid; d < 300; d += 256) xs[r * 300 + d] = src[d];
  }
  for (int r = L; r < ROWS; ++r)
    for (int d = tid; d < 300; d += 256) xs[r * 300 + d] = 0.0f;
  __syncthreads();

  const int ty = tid >> 6;      // 0..3 : row group (wave-uniform)
  const int tx = tid & 63;      // 0..63: 4 filter cols each
  const int row0 = ty * RT;
  float acc[RT][4];
#pragma unroll
  for (int r = 0; r < RT; ++r)
#pragma unroll
    for (int c = 0; c < 4; ++c) acc[r][c] = 0.0f;

  for (int d = 0; d < 300; ++d) {
    const float4 b0 = *(const float4*)(fT + (size_t)(0 * 300 + d) * 256 + tx * 4);
    const float4 b1 = *(const float4*)(fT + (size_t)(300 + d) * 256 + tx * 4);
    const float4 b2 = *(const float4*)(fT + (size_t)(600 + d) * 256 + tx * 4);
    float a[RT + 2];
#pragma unroll
    for (int r = 0; r < RT + 2; ++r) a[r] = xs[(row0 + r) * 300 + d];  // wave-uniform broadcast
#pragma unroll
    for (int r = 0; r < RT; ++r) {
      acc[r][0] += a[r] * b0.x + a[r + 1] * b1.x + a[r + 2] * b2.x;
      acc[r][1] += a[r] * b0.y + a[r + 1] * b1.y + a[r + 2] * b2.y;
      acc[r][2] += a[r] * b0.z + a[r + 1] * b1.z + a[r + 2] * b2.z;
      acc[r][3] += a[r] * b0.w + a[r + 1] * b1.w + a[r + 2] * b2.w;
    }
  }
#pragma unroll
  for (int r = 0; r < RT; ++r) {
    int j = row0 + r;
    if (j < L) {
      float4 v = make_float4(acc[r][0], acc[r][1], acc[r][2], acc[r][3]);
      *(float4*)(out + ((size_t)seq * L + j) * 256 + tx * 4) = v;
    }
  }
}

// One block per (b,s): cosine sims, duplicate-safe top-5 pool, sigmoid, mean -> out[1+bs]
__global__ __launch_bounds__(256) void k_sim(const int* __restrict__ question,
                                             const int* __restrict__ sentences,
                                             const float* __restrict__ oneh,
                                             const float* __restrict__ embeds,
                                             const float* __restrict__ qc_g,
                                             const float* __restrict__ sc_g,
                                             const float* __restrict__ lin_w,
                                             const float* __restrict__ lin_b,
                                             float* __restrict__ out) {
  const int bs = blockIdx.x;
  const int b = bs >> 5;
  const int tid = threadIdx.x;

  __shared__ float bufS[40 * 301];   // se (stride 301) then sc (stride 257)
  __shared__ float bufQ[30 * 301];   // qe (stride 301) then qc (stride 257)
  __shared__ float sim1[1200];
  __shared__ float sim2[1200];
  __shared__ float ohl[1200];
  __shared__ float normQ[32], normS[40];
  __shared__ float feats[30][6];
  __shared__ float lo[30];

  const int* stok = sentences + (size_t)bs * 40;
  const int* qtok = question + (size_t)b * 30;
  for (int r = 0; r < 40; ++r) {
    const float* src = embeds + (size_t)stok[r] * 300;
    for (int d = tid; d < 300; d += 256) bufS[r * 301 + d] = src[d];
  }
  for (int r = 0; r < 30; ++r) {
    const float* src = embeds + (size_t)qtok[r] * 300;
    for (int d = tid; d < 300; d += 256) bufQ[r * 301 + d] = src[d];
  }
  {
    const float* og = oneh + (size_t)bs * 1200;
    for (int i = tid; i < 1200; i += 256) ohl[i] = og[i];
  }
  __syncthreads();
  if (tid < 30) {
    float sum = 0.f;
    for (int d = 0; d < 300; ++d) { float v = bufQ[tid * 301 + d]; sum += v * v; }
    normQ[tid] = sqrtf(sum);
  } else if (tid < 70) {
    int r = tid - 30;
    float sum = 0.f;
    for (int d = 0; d < 300; ++d) { float v = bufS[r * 301 + d]; sum += v * v; }
    normS[r] = sqrtf(sum);
  }
  __syncthreads();
  for (int e = tid; e < 1200; e += 256) {
    int q = e / 40, l = e - q * 40;
    const float* qp = bufQ + q * 301;
    const float* sp = bufS + l * 301;
    float dot = 0.f;
    for (int d = 0; d < 300; ++d) dot += qp[d] * sp[d];
    sim1[e] = dot / (normQ[q] * normS[l]);
  }
  __syncthreads();
  {
    const float* qcp = qc_g + (size_t)b * 30 * 256;
    for (int i = tid; i < 30 * 256; i += 256) bufQ[(i >> 8) * 257 + (i & 255)] = qcp[i];
    const float* scp = sc_g + (size_t)bs * 40 * 256;
    for (int i = tid; i < 40 * 256; i += 256) bufS[(i >> 8) * 257 + (i & 255)] = scp[i];
  }
  __syncthreads();
  if (tid < 30) {
    float sum = 0.f;
    for (int d = 0; d < 256; ++d) { float v = bufQ[tid * 257 + d]; sum += v * v; }
    normQ[tid] = sqrtf(sum);
  } else if (tid < 70) {
    int r = tid - 30;
    float sum = 0.f;
    for (int d = 0; d < 256; ++d) { float v = bufS[r * 257 + d]; sum += v * v; }
    normS[r] = sqrtf(sum);
  }
  __syncthreads();
  for (int e = tid; e < 1200; e += 256) {
    int q = e / 40, l = e - q * 40;
    const float* qp = bufQ + q * 257;
    const float* sp = bufS + l * 257;
    float dot = 0.f;
    for (int d = 0; d < 256; ++d) dot += qp[d] * sp[d];
    sim2[e] = dot / (normQ[q] * normS[l]);
  }
  __syncthreads();
  if (tid < 90) {
    const int m = tid / 30, q = tid - m * 30;
    const float* row = (m == 0) ? (sim1 + q * 40) : (m == 1) ? (sim2 + q * 40) : (ohl + q * 40);
    // duplicate-safe top-5: descending value passes with counts
    float thr = 3.4e38f;
    int got = 0;
    float sum = 0.f, maxv = 0.f;
    while (got < 5) {
      float mx = -3.4e38f;
      int c = 0;
      for (int l = 0; l < 40; ++l) {
        float v = row[l];
        if (v < thr) {
          if (v > mx) { mx = v; c = 1; }
          else if (v == mx) { c++; }
        }
      }
      if (c == 0) break;  // safety: never hang (only reachable with NaN data)
      if (got == 0) maxv = mx;
      int take = (c < 5 - got) ? c : (5 - got);
      sum += mx * (float)take;
      got += take;
      thr = mx;
    }
    feats[q][m * 2 + 0] = maxv;
    feats[q][m * 2 + 1] = sum * 0.2f;
  }
  __syncthreads();
  if (tid < 30) {
    float z = lin_b[0];
#pragma unroll
    for (int i = 0; i < 6; ++i) z += feats[tid][i] * lin_w[i];
    lo[tid] = 1.0f / (1.0f + expf(-z));
  }
  __syncthreads();
  if (tid == 0) {
    float sum = 0.f;
    for (int q = 0; q < 30; ++q) sum += lo[q];
    out[1 + bs] = sum * (1.0f / 30.0f);
  }
}

__global__ __launch_bounds__(256) void k_loss(const int* __restrict__ tsent,
                                              const int* __restrict__ tdoc,
                                              float* __restrict__ out) {
  __shared__ float red[256];
  __shared__ float sent_loss_sh;
  const int tid = threadIdx.x;
  float local = 0.f;
  for (int i = tid; i < 1024; i += 256) {
    float p = out[1 + i];
    float t = (float)tsent[i];
    float lp = fmaxf(logf(p), -100.f);
    float l1 = fmaxf(logf(1.f - p), -100.f);
    local += -(t * lp + (1.f - t) * l1);
  }
  red[tid] = local;
  __syncthreads();
  for (int off = 128; off > 0; off >>= 1) {
    if (tid < off) red[tid] += red[tid + off];
    __syncthreads();
  }
  if (tid == 0) sent_loss_sh = red[0] * (1.0f / 1024.0f);
  __syncthreads();
  float dterm = 0.f;
  if (tid < 32) {
    float mx = out[1 + tid * 32];
    for (int s2 = 1; s2 < 32; ++s2) mx = fmaxf(mx, out[1 + tid * 32 + s2]);
    out[1025 + tid] = mx;
    float t = (float)tdoc[tid];
    float lp = fmaxf(logf(mx), -100.f);
    float l1 = fmaxf(logf(1.f - mx), -100.f);
    dterm = -(t * lp + (1.f - t) * l1);
  }
  red[tid] = dterm;
  __syncthreads();
  for (int off = 128; off > 0; off >>= 1) {
    if (tid < off) red[tid] += red[tid + off];
    __syncthreads();
  }
  if (tid == 0) out[0] = 0.5f * (sent_loss_sh + red[0] * (1.0f / 32.0f));
}

extern "C" void kernel_launch(void* const* d_in, const int* in_sizes, int n_in,
                              void* d_out, int out_size, void* d_ws, size_t ws_size,
                              hipStream_t stream) {
  const int*   question     = (const int*)d_in[0];
  const int*   sentences    = (const int*)d_in[1];
  const int*   target_sents = (const int*)d_in[2];
  const int*   target_docs  = (const int*)d_in[3];
  const float* oneh         = (const float*)d_in[4];
  const float* embeds       = (const float*)d_in[5];
  const float* filters      = (const float*)d_in[6];
  const float* lin_w        = (const float*)d_in[7];
  const float* lin_b        = (const float*)d_in[8];
  float* out = (float*)d_out;
  float* ws  = (float*)d_ws;

  float* fT = ws;                          // 900*256          = 230400 floats
  float* sc = fT + 230400;                 // 1024*40*256      = 10485760 floats
  float* qc = sc + 10485760;               // 32*30*256        = 245760 floats

  k_transpose_filters<<<900, 256, 0, stream>>>(filters, fT);
  k_conv<40, 10><<<1024, 256, 0, stream>>>(sentences, embeds, fT, sc);
  k_conv<30, 8><<<32, 256, 0, stream>>>(question, embeds, fT, qc);
  k_sim<<<1024, 256, 0, stream>>>(question, sentences, oneh, embeds, qc, sc,
                                  lin_w, lin_b, out);
  k_loss<<<1, 256, 0, stream>>>(target_sents, target_docs, out);
}

// Round 3
// 462.477 us; speedup vs baseline: 1.8010x; 1.8010x over previous
//
#include <hip/hip_runtime.h>
#include <math.h>

// B=32, S=32, LQ=30, LS=40, D=300, F=256, FS=3, K=5
// out layout: [0]=total_loss, [1..1024]=sent_output(B,S), [1025..1056]=doc_em(B)

typedef __attribute__((ext_vector_type(4))) float f32x4;
typedef __attribute__((ext_vector_type(8))) short s16x8;

__device__ inline ushort bf16rne(float f) {
  unsigned u = __float_as_uint(f);
  u += 0x7fff + ((u >> 16) & 1);
  return (ushort)(u >> 16);
}

// Pack filters into MFMA B-fragment-major layout:
// fB[((tap*10+kstep)*16 + nt)*64 + lane][8] ; B[k][col]: col=lane&15, k=(lane>>4)*8+i
__global__ __launch_bounds__(64) void k_prepB(const float* __restrict__ filters,
                                              ushort* __restrict__ fB) {
  const int bid = blockIdx.x;            // (tap*10+kstep)*16 + nt, 480 total
  const int lane = threadIdx.x;
  const int nt = bid & 15;
  const int tk = bid >> 4;
  const int tap = tk / 10, kstep = tk - tap * 10;
  const int f = nt * 16 + (lane & 15);
  const int kb = kstep * 32 + (lane >> 4) * 8;
  uint p[4];
#pragma unroll
  for (int h = 0; h < 4; ++h) {
    int d0 = kb + h * 2, d1 = kb + h * 2 + 1;
    float v0 = (d0 < 300) ? filters[(size_t)f * 900 + tap * 300 + d0] : 0.f;
    float v1 = (d1 < 300) ? filters[(size_t)f * 900 + tap * 300 + d1] : 0.f;
    p[h] = (uint)bf16rne(v0) | ((uint)bf16rne(v1) << 16);
  }
  uint4* dst = (uint4*)(fB + ((size_t)bid * 64 + lane) * 8);
  *dst = make_uint4(p[0], p[1], p[2], p[3]);
}

// MFMA conv: 2 sequences per block, 4 waves (wave w owns filter cols w*64..w*64+63).
// out[j,f] = sum_{tap} sum_{d<300} X[j+tap][d] * W[f][tap][d], rows >= L are zero.
template<int L, int MT, int ROWS_ST>
__global__ __launch_bounds__(256) void k_conv_mfma(const int* __restrict__ tokens,
                                                   const float* __restrict__ embeds,
                                                   const ushort* __restrict__ fB,
                                                   float* __restrict__ out) {
  constexpr int R320 = ROWS_ST * 320;
  __shared__ __align__(16) ushort xs[2 * R320];
  const int tid = threadIdx.x;
  const int seq0 = blockIdx.x * 2;

  // Stage X as bf16, XOR-swizzled (idx ^= (row&7)<<3 : 16B granules across banks)
  for (int idx = tid; idx < 2 * ROWS_ST * 160; idx += 256) {
    int seq = idx / (ROWS_ST * 160);
    int rem = idx - seq * (ROWS_ST * 160);
    int row = rem / 160;
    int s = rem - row * 160;
    int d = s * 2;
    float v0 = 0.f, v1 = 0.f;
    if (row < L && d < 300) {
      const float2 v = *(const float2*)(embeds + (size_t)tokens[(seq0 + seq) * L + row] * 300 + d);
      v0 = v.x; v1 = v.y;
    }
    uint p = (uint)bf16rne(v0) | ((uint)bf16rne(v1) << 16);
    int flat = seq * R320 + row * 320 + d;
    int swz = flat ^ ((row & 7) << 3);
    *(uint*)(xs + swz) = p;
  }
  __syncthreads();

  const int wv = tid >> 6, lane = tid & 63;
  const int lr = lane & 15, lh = lane >> 4;

  f32x4 acc[2][MT][4];
#pragma unroll
  for (int seq = 0; seq < 2; ++seq)
#pragma unroll
    for (int mt = 0; mt < MT; ++mt)
#pragma unroll
      for (int n = 0; n < 4; ++n)
#pragma unroll
        for (int r = 0; r < 4; ++r) acc[seq][mt][n][r] = 0.f;

  const s16x8* fBv = (const s16x8*)fB;
  for (int kstep = 0; kstep < 10; ++kstep) {
#pragma unroll
    for (int tap = 0; tap < 3; ++tap) {
      s16x8 b[4];
#pragma unroll
      for (int n = 0; n < 4; ++n)
        b[n] = fBv[((size_t)((tap * 10 + kstep) * 16 + (wv * 4 + n))) * 64 + lane];
      s16x8 a[2][MT];
#pragma unroll
      for (int seq = 0; seq < 2; ++seq)
#pragma unroll
        for (int mt = 0; mt < MT; ++mt) {
          int row = mt * 16 + lr + tap;
          int flat = seq * R320 + row * 320 + kstep * 32 + lh * 8;
          int swz = flat ^ ((row & 7) << 3);
          a[seq][mt] = *(const s16x8*)(xs + swz);
        }
#pragma unroll
      for (int seq = 0; seq < 2; ++seq)
#pragma unroll
        for (int mt = 0; mt < MT; ++mt)
#pragma unroll
          for (int n = 0; n < 4; ++n)
            acc[seq][mt][n] = __builtin_amdgcn_mfma_f32_16x16x32_bf16(
                a[seq][mt], b[n], acc[seq][mt][n], 0, 0, 0);
    }
  }

  // C/D: col = lane&15, row = (lane>>4)*4 + reg (m89-verified)
#pragma unroll
  for (int seq = 0; seq < 2; ++seq)
#pragma unroll
    for (int mt = 0; mt < MT; ++mt)
#pragma unroll
      for (int n = 0; n < 4; ++n)
#pragma unroll
        for (int r = 0; r < 4; ++r) {
          int j = mt * 16 + lh * 4 + r;
          if (j < L)
            out[((size_t)(seq0 + seq) * L + j) * 256 + wv * 64 + n * 16 + lr] =
                acc[seq][mt][n][r];
        }
}

// One block per (b,s): cosine sims, duplicate-safe top-5 pool, sigmoid, mean -> out[1+bs]
__global__ __launch_bounds__(256) void k_sim(const int* __restrict__ question,
                                             const int* __restrict__ sentences,
                                             const float* __restrict__ oneh,
                                             const float* __restrict__ embeds,
                                             const float* __restrict__ qc_g,
                                             const float* __restrict__ sc_g,
                                             const float* __restrict__ lin_w,
                                             const float* __restrict__ lin_b,
                                             float* __restrict__ out) {
  const int bs = blockIdx.x;
  const int b = bs >> 5;
  const int tid = threadIdx.x;

  __shared__ float bufS[40 * 301];   // se (stride 301) then sc (stride 257)
  __shared__ float bufQ[30 * 301];   // qe (stride 301) then qc (stride 257)
  __shared__ float sim1[1200];
  __shared__ float sim2[1200];
  __shared__ float ohl[1200];
  __shared__ float normQ[32], normS[40];
  __shared__ float feats[30][6];
  __shared__ float lo[30];

  const int* stok = sentences + (size_t)bs * 40;
  const int* qtok = question + (size_t)b * 30;
  for (int r = 0; r < 40; ++r) {
    const float* src = embeds + (size_t)stok[r] * 300;
    for (int d = tid; d < 300; d += 256) bufS[r * 301 + d] = src[d];
  }
  for (int r = 0; r < 30; ++r) {
    const float* src = embeds + (size_t)qtok[r] * 300;
    for (int d = tid; d < 300; d += 256) bufQ[r * 301 + d] = src[d];
  }
  {
    const float* og = oneh + (size_t)bs * 1200;
    for (int i = tid; i < 1200; i += 256) ohl[i] = og[i];
  }
  __syncthreads();
  if (tid < 30) {
    float sum = 0.f;
    for (int d = 0; d < 300; ++d) { float v = bufQ[tid * 301 + d]; sum += v * v; }
    normQ[tid] = sqrtf(sum);
  } else if (tid < 70) {
    int r = tid - 30;
    float sum = 0.f;
    for (int d = 0; d < 300; ++d) { float v = bufS[r * 301 + d]; sum += v * v; }
    normS[r] = sqrtf(sum);
  }
  __syncthreads();
  for (int e = tid; e < 1200; e += 256) {
    int q = e / 40, l = e - q * 40;
    const float* qp = bufQ + q * 301;
    const float* sp = bufS + l * 301;
    float dot = 0.f;
    for (int d = 0; d < 300; ++d) dot += qp[d] * sp[d];
    sim1[e] = dot / (normQ[q] * normS[l]);
  }
  __syncthreads();
  {
    const float* qcp = qc_g + (size_t)b * 30 * 256;
    for (int i = tid; i < 30 * 256; i += 256) bufQ[(i >> 8) * 257 + (i & 255)] = qcp[i];
    const float* scp = sc_g + (size_t)bs * 40 * 256;
    for (int i = tid; i < 40 * 256; i += 256) bufS[(i >> 8) * 257 + (i & 255)] = scp[i];
  }
  __syncthreads();
  if (tid < 30) {
    float sum = 0.f;
    for (int d = 0; d < 256; ++d) { float v = bufQ[tid * 257 + d]; sum += v * v; }
    normQ[tid] = sqrtf(sum);
  } else if (tid < 70) {
    int r = tid - 30;
    float sum = 0.f;
    for (int d = 0; d < 256; ++d) { float v = bufS[r * 257 + d]; sum += v * v; }
    normS[r] = sqrtf(sum);
  }
  __syncthreads();
  for (int e = tid; e < 1200; e += 256) {
    int q = e / 40, l = e - q * 40;
    const float* qp = bufQ + q * 257;
    const float* sp = bufS + l * 257;
    float dot = 0.f;
    for (int d = 0; d < 256; ++d) dot += qp[d] * sp[d];
    sim2[e] = dot / (normQ[q] * normS[l]);
  }
  __syncthreads();
  if (tid < 90) {
    const int m = tid / 30, q = tid - m * 30;
    const float* row = (m == 0) ? (sim1 + q * 40) : (m == 1) ? (sim2 + q * 40) : (ohl + q * 40);
    // duplicate-safe top-5: descending value passes with counts
    float thr = 3.4e38f;
    int got = 0;
    float sum = 0.f, maxv = 0.f;
    while (got < 5) {
      float mx = -3.4e38f;
      int c = 0;
      for (int l = 0; l < 40; ++l) {
        float v = row[l];
        if (v < thr) {
          if (v > mx) { mx = v; c = 1; }
          else if (v == mx) { c++; }
        }
      }
      if (c == 0) break;  // safety: never hang
      if (got == 0) maxv = mx;
      int take = (c < 5 - got) ? c : (5 - got);
      sum += mx * (float)take;
      got += take;
      thr = mx;
    }
    feats[q][m * 2 + 0] = maxv;
    feats[q][m * 2 + 1] = sum * 0.2f;
  }
  __syncthreads();
  if (tid < 30) {
    float z = lin_b[0];
#pragma unroll
    for (int i = 0; i < 6; ++i) z += feats[tid][i] * lin_w[i];
    lo[tid] = 1.0f / (1.0f + expf(-z));
  }
  __syncthreads();
  if (tid == 0) {
    float sum = 0.f;
    for (int q = 0; q < 30; ++q) sum += lo[q];
    out[1 + bs] = sum * (1.0f / 30.0f);
  }
}

__global__ __launch_bounds__(256) void k_loss(const int* __restrict__ tsent,
                                              const int* __restrict__ tdoc,
                                              float* __restrict__ out) {
  __shared__ float red[256];
  __shared__ float sent_loss_sh;
  const int tid = threadIdx.x;
  float local = 0.f;
  for (int i = tid; i < 1024; i += 256) {
    float p = out[1 + i];
    float t = (float)tsent[i];
    float lp = fmaxf(logf(p), -100.f);
    float l1 = fmaxf(logf(1.f - p), -100.f);
    local += -(t * lp + (1.f - t) * l1);
  }
  red[tid] = local;
  __syncthreads();
  for (int off = 128; off > 0; off >>= 1) {
    if (tid < off) red[tid] += red[tid + off];
    __syncthreads();
  }
  if (tid == 0) sent_loss_sh = red[0] * (1.0f / 1024.0f);
  __syncthreads();
  float dterm = 0.f;
  if (tid < 32) {
    float mx = out[1 + tid * 32];
    for (int s2 = 1; s2 < 32; ++s2) mx = fmaxf(mx, out[1 + tid * 32 + s2]);
    out[1025 + tid] = mx;
    float t = (float)tdoc[tid];
    float lp = fmaxf(logf(mx), -100.f);
    float l1 = fmaxf(logf(1.f - mx), -100.f);
    dterm = -(t * lp + (1.f - t) * l1);
  }
  red[tid] = dterm;
  __syncthreads();
  for (int off = 128; off > 0; off >>= 1) {
    if (tid < off) red[tid] += red[tid + off];
    __syncthreads();
  }
  if (tid == 0) out[0] = 0.5f * (sent_loss_sh + red[0] * (1.0f / 32.0f));
}

extern "C" void kernel_launch(void* const* d_in, const int* in_sizes, int n_in,
                              void* d_out, int out_size, void* d_ws, size_t ws_size,
                              hipStream_t stream) {
  const int*   question     = (const int*)d_in[0];
  const int*   sentences    = (const int*)d_in[1];
  const int*   target_sents = (const int*)d_in[2];
  const int*   target_docs  = (const int*)d_in[3];
  const float* oneh         = (const float*)d_in[4];
  const float* embeds       = (const float*)d_in[5];
  const float* filters      = (const float*)d_in[6];
  const float* lin_w        = (const float*)d_in[7];
  const float* lin_b        = (const float*)d_in[8];
  float* out = (float*)d_out;

  ushort* fB = (ushort*)d_ws;              // 480*64*8 = 245760 bf16 (491.5 KB)
  float*  sc = (float*)((char*)d_ws + 491520);   // 1024*40*256 f32
  float*  qc = sc + 10485760;              // 32*30*256 f32

  k_prepB<<<480, 64, 0, stream>>>(filters, fB);
  k_conv_mfma<40, 3, 50><<<512, 256, 0, stream>>>(sentences, embeds, fB, sc);
  k_conv_mfma<30, 2, 34><<<16, 256, 0, stream>>>(question, embeds, fB, qc);
  k_sim<<<1024, 256, 0, stream>>>(question, sentences, oneh, embeds, qc, sc,
                                  lin_w, lin_b, out);
  k_loss<<<1, 256, 0, stream>>>(target_sents, target_docs, out);
}

// Round 4
// 216.298 us; speedup vs baseline: 3.8508x; 2.1381x over previous
//
#include <hip/hip_runtime.h>
#include <math.h>

// B=32, S=32, LQ=30, LS=40, D=300, F=256, FS=3, K=5
// out layout: [0]=total_loss, [1..1024]=sent_output(B,S), [1025..1056]=doc_em(B)

typedef __attribute__((ext_vector_type(4))) float f32x4;
typedef __attribute__((ext_vector_type(8))) short s16x8;

__device__ inline ushort bf16rne(float f) {
  unsigned u = __float_as_uint(f);
  u += 0x7fff + ((u >> 16) & 1);
  return (ushort)(u >> 16);
}
__device__ inline uint pack2(float a, float b) {
  return (uint)bf16rne(a) | ((uint)bf16rne(b) << 16);
}
__device__ inline float ubf(short h) { return __uint_as_float(((uint)(ushort)h) << 16); }

// Pack filters into MFMA B-fragment-major layout:
// fB[((tap*10+kstep)*16 + nt)*64 + lane][8] ; B[k][col]: col=lane&15, k=(lane>>4)*8+i
__global__ __launch_bounds__(64) void k_prepB(const float* __restrict__ filters,
                                              ushort* __restrict__ fB) {
  const int bid = blockIdx.x;            // (tap*10+kstep)*16 + nt, 480 total
  const int lane = threadIdx.x;
  const int nt = bid & 15;
  const int tk = bid >> 4;
  const int tap = tk / 10, kstep = tk - tap * 10;
  const int f = nt * 16 + (lane & 15);
  const int kb = kstep * 32 + (lane >> 4) * 8;
  uint p[4];
#pragma unroll
  for (int h = 0; h < 4; ++h) {
    int d0 = kb + h * 2, d1 = kb + h * 2 + 1;
    float v0 = (d0 < 300) ? filters[(size_t)f * 900 + tap * 300 + d0] : 0.f;
    float v1 = (d1 < 300) ? filters[(size_t)f * 900 + tap * 300 + d1] : 0.f;
    p[h] = (uint)bf16rne(v0) | ((uint)bf16rne(v1) << 16);
  }
  uint4* dst = (uint4*)(fB + ((size_t)bid * 64 + lane) * 8);
  *dst = make_uint4(p[0], p[1], p[2], p[3]);
}

// MFMA conv: 2 sequences per block, 4 waves (wave w owns filter cols w*64..w*64+63).
template<int L, int MT, int ROWS_ST>
__global__ __launch_bounds__(256) void k_conv_mfma(const int* __restrict__ tokens,
                                                   const float* __restrict__ embeds,
                                                   const ushort* __restrict__ fB,
                                                   float* __restrict__ out) {
  constexpr int R320 = ROWS_ST * 320;
  __shared__ __align__(16) ushort xs[2 * R320];
  const int tid = threadIdx.x;
  const int seq0 = blockIdx.x * 2;

  for (int idx = tid; idx < 2 * ROWS_ST * 160; idx += 256) {
    int seq = idx / (ROWS_ST * 160);
    int rem = idx - seq * (ROWS_ST * 160);
    int row = rem / 160;
    int s = rem - row * 160;
    int d = s * 2;
    float v0 = 0.f, v1 = 0.f;
    if (row < L && d < 300) {
      const float2 v = *(const float2*)(embeds + (size_t)tokens[(seq0 + seq) * L + row] * 300 + d);
      v0 = v.x; v1 = v.y;
    }
    uint p = pack2(v0, v1);
    int flat = seq * R320 + row * 320 + d;
    int swz = flat ^ ((row & 7) << 3);
    *(uint*)(xs + swz) = p;
  }
  __syncthreads();

  const int wv = tid >> 6, lane = tid & 63;
  const int lr = lane & 15, lh = lane >> 4;

  f32x4 acc[2][MT][4];
#pragma unroll
  for (int seq = 0; seq < 2; ++seq)
#pragma unroll
    for (int mt = 0; mt < MT; ++mt)
#pragma unroll
      for (int n = 0; n < 4; ++n)
#pragma unroll
        for (int r = 0; r < 4; ++r) acc[seq][mt][n][r] = 0.f;

  const s16x8* fBv = (const s16x8*)fB;
  for (int kstep = 0; kstep < 10; ++kstep) {
#pragma unroll
    for (int tap = 0; tap < 3; ++tap) {
      s16x8 b[4];
#pragma unroll
      for (int n = 0; n < 4; ++n)
        b[n] = fBv[((size_t)((tap * 10 + kstep) * 16 + (wv * 4 + n))) * 64 + lane];
      s16x8 a[2][MT];
#pragma unroll
      for (int seq = 0; seq < 2; ++seq)
#pragma unroll
        for (int mt = 0; mt < MT; ++mt) {
          int row = mt * 16 + lr + tap;
          int flat = seq * R320 + row * 320 + kstep * 32 + lh * 8;
          int swz = flat ^ ((row & 7) << 3);
          a[seq][mt] = *(const s16x8*)(xs + swz);
        }
#pragma unroll
      for (int seq = 0; seq < 2; ++seq)
#pragma unroll
        for (int mt = 0; mt < MT; ++mt)
#pragma unroll
          for (int n = 0; n < 4; ++n)
            acc[seq][mt][n] = __builtin_amdgcn_mfma_f32_16x16x32_bf16(
                a[seq][mt], b[n], acc[seq][mt][n], 0, 0, 0);
    }
  }

#pragma unroll
  for (int seq = 0; seq < 2; ++seq)
#pragma unroll
    for (int mt = 0; mt < MT; ++mt)
#pragma unroll
      for (int n = 0; n < 4; ++n)
#pragma unroll
        for (int r = 0; r < 4; ++r) {
          int j = mt * 16 + lh * 4 + r;
          if (j < L)
            out[((size_t)(seq0 + seq) * L + j) * 256 + wv * 64 + n * 16 + lr] =
                acc[seq][mt][n][r];
        }
}

// One block per (b,s): bf16-MFMA cosine sims + duplicate-safe top-5 pool + sigmoid + mean
__global__ __launch_bounds__(256) void k_sim(const int* __restrict__ question,
                                             const int* __restrict__ sentences,
                                             const float* __restrict__ oneh,
                                             const float* __restrict__ embeds,
                                             const float* __restrict__ qc_g,
                                             const float* __restrict__ sc_g,
                                             const float* __restrict__ lin_w,
                                             const float* __restrict__ lin_b,
                                             float* __restrict__ out) {
  const int bs = blockIdx.x;
  const int b = bs >> 5;
  const int tid = threadIdx.x;
  const int wv = tid >> 6, lane = tid & 63;
  const int lr = lane & 15, lh = lane >> 4;

  __shared__ __align__(16) ushort qx[32 * 320];   // 20 KB (Q-side rows, swizzled bf16)
  __shared__ __align__(16) ushort sx[48 * 320];   // 30 KB (S-side rows, swizzled bf16)
  __shared__ float simb[2][30][49];               // stride 49: conflict-free pooling
  __shared__ float ohl[30 * 41];                  // stride 41
  __shared__ float rcpQ[32], rcpS[48];
  __shared__ float feats[30][6];
  __shared__ float lo[30];

  const int* qtok = question + (size_t)b * 30;
  const int* stok = sentences + (size_t)bs * 40;

  // stage one-hot (stride 41)
  {
    const float* og = oneh + (size_t)bs * 1200;
    for (int i = tid; i < 1200; i += 256) {
      int q = i / 40, l = i - q * 40;
      ohl[q * 41 + l] = og[i];
    }
  }

  for (int ph = 0; ph < 2; ++ph) {
    // ---- stage Q-side (32 rows) and S-side (48 rows), 320 cols, zero-padded ----
    if (ph == 0) {
      for (int idx = tid; idx < 32 * 80; idx += 256) {
        int row = idx / 80, s = idx - row * 80, d = s * 4;
        float4 v = make_float4(0.f, 0.f, 0.f, 0.f);
        if (row < 30 && d < 300) v = *(const float4*)(embeds + (size_t)qtok[row] * 300 + d);
        int flat = row * 320 + d;
        int swz = flat ^ ((row & 7) << 3);
        *(uint2*)(qx + swz) = make_uint2(pack2(v.x, v.y), pack2(v.z, v.w));
      }
      for (int idx = tid; idx < 48 * 80; idx += 256) {
        int row = idx / 80, s = idx - row * 80, d = s * 4;
        float4 v = make_float4(0.f, 0.f, 0.f, 0.f);
        if (row < 40 && d < 300) v = *(const float4*)(embeds + (size_t)stok[row] * 300 + d);
        int flat = row * 320 + d;
        int swz = flat ^ ((row & 7) << 3);
        *(uint2*)(sx + swz) = make_uint2(pack2(v.x, v.y), pack2(v.z, v.w));
      }
    } else {
      for (int idx = tid; idx < 32 * 80; idx += 256) {
        int row = idx / 80, s = idx - row * 80, d = s * 4;
        float4 v = make_float4(0.f, 0.f, 0.f, 0.f);
        if (row < 30 && d < 256) v = *(const float4*)(qc_g + ((size_t)b * 30 + row) * 256 + d);
        int flat = row * 320 + d;
        int swz = flat ^ ((row & 7) << 3);
        *(uint2*)(qx + swz) = make_uint2(pack2(v.x, v.y), pack2(v.z, v.w));
      }
      for (int idx = tid; idx < 48 * 80; idx += 256) {
        int row = idx / 80, s = idx - row * 80, d = s * 4;
        float4 v = make_float4(0.f, 0.f, 0.f, 0.f);
        if (row < 40 && d < 256) v = *(const float4*)(sc_g + ((size_t)bs * 40 + row) * 256 + d);
        int flat = row * 320 + d;
        int swz = flat ^ ((row & 7) << 3);
        *(uint2*)(sx + swz) = make_uint2(pack2(v.x, v.y), pack2(v.z, v.w));
      }
    }
    __syncthreads();

    const int KS = ph ? 8 : 10;
    f32x4 acc[2];
    acc[0] = (f32x4){0.f, 0.f, 0.f, 0.f};
    acc[1] = (f32x4){0.f, 0.f, 0.f, 0.f};
    if (wv < 3) {
      // wave wv = N-tile; mt in {0,1}
      for (int kstep = 0; kstep < KS; ++kstep) {
        int brow = wv * 16 + lr;
        int bflat = brow * 320 + kstep * 32 + lh * 8;
        s16x8 bf = *(const s16x8*)(sx + (bflat ^ ((brow & 7) << 3)));
#pragma unroll
        for (int mt = 0; mt < 2; ++mt) {
          int arow = mt * 16 + lr;
          int aflat = arow * 320 + kstep * 32 + lh * 8;
          s16x8 af = *(const s16x8*)(qx + (aflat ^ ((arow & 7) << 3)));
          acc[mt] = __builtin_amdgcn_mfma_f32_16x16x32_bf16(af, bf, acc[mt], 0, 0, 0);
        }
      }
    } else {
      // wave 3: row-norm reciprocals from the same bf16 data (consistent rounding)
      int t2 = lane;
      if (t2 < 32) {
        float s = 0.f;
        for (int c = 0; c < 40; ++c) {
          int flat = t2 * 320 + c * 8;
          s16x8 v = *(const s16x8*)(qx + (flat ^ ((t2 & 7) << 3)));
#pragma unroll
          for (int i = 0; i < 8; ++i) { float f = ubf(v[i]); s += f * f; }
        }
        rcpQ[t2] = (s > 0.f) ? rsqrtf(s) : 0.f;
      } else {
        int r0 = t2 - 32;
#pragma unroll
        for (int rr = 0; rr < 2; ++rr) {
          int row = r0 + rr * 32;
          if (row < 48) {
            float s = 0.f;
            for (int c = 0; c < 40; ++c) {
              int flat = row * 320 + c * 8;
              s16x8 v = *(const s16x8*)(sx + (flat ^ ((row & 7) << 3)));
#pragma unroll
              for (int i = 0; i < 8; ++i) { float f = ubf(v[i]); s += f * f; }
            }
            rcpS[row] = (s > 0.f) ? rsqrtf(s) : 0.f;
          }
        }
      }
    }
    __syncthreads();   // rcp ready, all LDS reads of qx/sx complete

    if (wv < 3) {
#pragma unroll
      for (int mt = 0; mt < 2; ++mt)
#pragma unroll
        for (int r = 0; r < 4; ++r) {
          int q = mt * 16 + lh * 4 + r;
          int l = wv * 16 + lr;
          if (q < 30) simb[ph][q][l] = acc[mt][r] * rcpQ[q] * rcpS[l];
        }
    }
    __syncthreads();   // simb[ph] written before qx/sx restage + rcp overwrite
  }

  // ---- duplicate-safe top-5 pooling on 90 threads ----
  if (tid < 90) {
    const int m = tid / 30, q = tid - m * 30;
    const float* row = (m == 0) ? &simb[0][q][0] : (m == 1) ? &simb[1][q][0] : (ohl + q * 41);
    float thr = 3.4e38f;
    int got = 0;
    float sum = 0.f, maxv = 0.f;
    while (got < 5) {
      float mx = -3.4e38f;
      int c = 0;
      for (int l = 0; l < 40; ++l) {
        float v = row[l];
        if (v < thr) {
          if (v > mx) { mx = v; c = 1; }
          else if (v == mx) { c++; }
        }
      }
      if (c == 0) break;  // safety: never hang
      if (got == 0) maxv = mx;
      int take = (c < 5 - got) ? c : (5 - got);
      sum += mx * (float)take;
      got += take;
      thr = mx;
    }
    feats[q][m * 2 + 0] = maxv;
    feats[q][m * 2 + 1] = sum * 0.2f;
  }
  __syncthreads();
  if (tid < 30) {
    float z = lin_b[0];
#pragma unroll
    for (int i = 0; i < 6; ++i) z += feats[tid][i] * lin_w[i];
    lo[tid] = 1.0f / (1.0f + expf(-z));
  }
  __syncthreads();
  if (tid == 0) {
    float sum = 0.f;
    for (int q = 0; q < 30; ++q) sum += lo[q];
    out[1 + bs] = sum * (1.0f / 30.0f);
  }
}

__global__ __launch_bounds__(256) void k_loss(const int* __restrict__ tsent,
                                              const int* __restrict__ tdoc,
                                              float* __restrict__ out) {
  __shared__ float red[256];
  __shared__ float sent_loss_sh;
  const int tid = threadIdx.x;
  float local = 0.f;
  for (int i = tid; i < 1024; i += 256) {
    float p = out[1 + i];
    float t = (float)tsent[i];
    float lp = fmaxf(logf(p), -100.f);
    float l1 = fmaxf(logf(1.f - p), -100.f);
    local += -(t * lp + (1.f - t) * l1);
  }
  red[tid] = local;
  __syncthreads();
  for (int off = 128; off > 0; off >>= 1) {
    if (tid < off) red[tid] += red[tid + off];
    __syncthreads();
  }
  if (tid == 0) sent_loss_sh = red[0] * (1.0f / 1024.0f);
  __syncthreads();
  float dterm = 0.f;
  if (tid < 32) {
    float mx = out[1 + tid * 32];
    for (int s2 = 1; s2 < 32; ++s2) mx = fmaxf(mx, out[1 + tid * 32 + s2]);
    out[1025 + tid] = mx;
    float t = (float)tdoc[tid];
    float lp = fmaxf(logf(mx), -100.f);
    float l1 = fmaxf(logf(1.f - mx), -100.f);
    dterm = -(t * lp + (1.f - t) * l1);
  }
  red[tid] = dterm;
  __syncthreads();
  for (int off = 128; off > 0; off >>= 1) {
    if (tid < off) red[tid] += red[tid + off];
    __syncthreads();
  }
  if (tid == 0) out[0] = 0.5f * (sent_loss_sh + red[0] * (1.0f / 32.0f));
}

extern "C" void kernel_launch(void* const* d_in, const int* in_sizes, int n_in,
                              void* d_out, int out_size, void* d_ws, size_t ws_size,
                              hipStream_t stream) {
  const int*   question     = (const int*)d_in[0];
  const int*   sentences    = (const int*)d_in[1];
  const int*   target_sents = (const int*)d_in[2];
  const int*   target_docs  = (const int*)d_in[3];
  const float* oneh         = (const float*)d_in[4];
  const float* embeds       = (const float*)d_in[5];
  const float* filters      = (const float*)d_in[6];
  const float* lin_w        = (const float*)d_in[7];
  const float* lin_b        = (const float*)d_in[8];
  float* out = (float*)d_out;

  ushort* fB = (ushort*)d_ws;              // 480*64*8 = 245760 bf16 (491.5 KB)
  float*  sc = (float*)((char*)d_ws + 491520);   // 1024*40*256 f32
  float*  qc = sc + 10485760;              // 32*30*256 f32

  k_prepB<<<480, 64, 0, stream>>>(filters, fB);
  k_conv_mfma<40, 3, 50><<<512, 256, 0, stream>>>(sentences, embeds, fB, sc);
  k_conv_mfma<30, 2, 34><<<16, 256, 0, stream>>>(question, embeds, fB, qc);
  k_sim<<<1024, 256, 0, stream>>>(question, sentences, oneh, embeds, qc, sc,
                                  lin_w, lin_b, out);
  k_loss<<<1, 256, 0, stream>>>(target_sents, target_docs, out);
}

// Round 5
// 189.605 us; speedup vs baseline: 4.3929x; 1.1408x over previous
//
#include <hip/hip_runtime.h>
#include <math.h>

// B=32, S=32, LQ=30, LS=40, D=300, F=256, FS=3, K=5
// out layout: [0]=total_loss, [1..1024]=sent_output(B,S), [1025..1056]=doc_em(B)

typedef __attribute__((ext_vector_type(4))) float f32x4;
typedef __attribute__((ext_vector_type(8))) short s16x8;

__device__ inline ushort bf16rne(float f) {
  unsigned u = __float_as_uint(f);
  u += 0x7fff + ((u >> 16) & 1);
  return (ushort)(u >> 16);
}
__device__ inline uint pack2(float a, float b) {
  return (uint)bf16rne(a) | ((uint)bf16rne(b) << 16);
}
__device__ inline float ubf(short h) { return __uint_as_float(((uint)(ushort)h) << 16); }

// Pack filters into MFMA B-fragment-major layout:
// fB[((tap*10+kstep)*16 + nt)*64 + lane][8] ; B[k][col]: col=lane&15, k=(lane>>4)*8+i
__global__ __launch_bounds__(64) void k_prepB(const float* __restrict__ filters,
                                              ushort* __restrict__ fB) {
  const int bid = blockIdx.x;            // (tap*10+kstep)*16 + nt, 480 total
  const int lane = threadIdx.x;
  const int nt = bid & 15;
  const int tk = bid >> 4;
  const int tap = tk / 10, kstep = tk - tap * 10;
  const int f = nt * 16 + (lane & 15);
  const int kb = kstep * 32 + (lane >> 4) * 8;
  uint p[4];
#pragma unroll
  for (int h = 0; h < 4; ++h) {
    int d0 = kb + h * 2, d1 = kb + h * 2 + 1;
    float v0 = (d0 < 300) ? filters[(size_t)f * 900 + tap * 300 + d0] : 0.f;
    float v1 = (d1 < 300) ? filters[(size_t)f * 900 + tap * 300 + d1] : 0.f;
    p[h] = (uint)bf16rne(v0) | ((uint)bf16rne(v1) << 16);
  }
  uint4* dst = (uint4*)(fB + ((size_t)bid * 64 + lane) * 8);
  *dst = make_uint4(p[0], p[1], p[2], p[3]);
}

// MFMA conv, 2 sequences per block, 4 waves. Also emits:
//  - blobA: embeds bf16 fragments   [seq][kstep<10][tile<MT][lane][8]  (sim phase 0)
//  - blobC: conv-out bf16 fragments [seq][kstep< 8][tile<MT][lane][8]  (sim phase 1)
//  - rcpA/rcpC: per-row 1/||x|| from the same bf16 data  [seq][row<L]
template<int L, int MT, int ROWS_ST>
__global__ __launch_bounds__(256) void k_conv_mfma(const int* __restrict__ tokens,
                                                   const float* __restrict__ embeds,
                                                   const ushort* __restrict__ fB,
                                                   ushort* __restrict__ blobA,
                                                   ushort* __restrict__ blobC,
                                                   float* __restrict__ rcpA,
                                                   float* __restrict__ rcpC) {
  constexpr int R320 = ROWS_ST * 320;
  __shared__ __align__(16) ushort xs[2 * R320];
  const int tid = threadIdx.x;
  const int seq0 = blockIdx.x * 2;

  // stage embeds rows as bf16, swizzled (flat ^ (row&7)<<3), zero-padded
  for (int idx = tid; idx < 2 * ROWS_ST * 160; idx += 256) {
    int seq = idx / (ROWS_ST * 160);
    int rem = idx - seq * (ROWS_ST * 160);
    int row = rem / 160;
    int s = rem - row * 160;
    int d = s * 2;
    float v0 = 0.f, v1 = 0.f;
    if (row < L && d < 300) {
      const float2 v = *(const float2*)(embeds + (size_t)tokens[(seq0 + seq) * L + row] * 300 + d);
      v0 = v.x; v1 = v.y;
    }
    uint p = pack2(v0, v1);
    int flat = seq * R320 + row * 320 + d;
    int swz = flat ^ ((row & 7) << 3);
    *(uint*)(xs + swz) = p;
  }
  __syncthreads();

  const int wv = tid >> 6, lane = tid & 63;
  const int lr = lane & 15, lh = lane >> 4;

  // ---- pack blobA (phase-0 sim fragments) ----
  {
    constexpr int T = 2 * 10 * MT;
    for (int t = wv; t < T; t += 4) {
      int seq = t / (10 * MT);
      int rem = t - seq * (10 * MT);
      int kstep = rem / MT, tile = rem - kstep * MT;
      int row = tile * 16 + lr;
      int flat = seq * R320 + row * 320 + kstep * 32 + lh * 8;
      s16x8 v = *(const s16x8*)(xs + (flat ^ ((row & 7) << 3)));
      *(s16x8*)(blobA + ((((size_t)(seq0 + seq) * 10 + kstep) * MT + tile) * 64 + lane) * 8) = v;
    }
  }
  // ---- phase-0 norms (cols 0..319, zeros past 300 harmless) ----
  if (tid < 2 * L) {
    int seq = tid / L, row = tid - seq * L;
    float s = 0.f;
    for (int c = 0; c < 40; ++c) {
      int flat = seq * R320 + row * 320 + c * 8;
      s16x8 v = *(const s16x8*)(xs + (flat ^ ((row & 7) << 3)));
#pragma unroll
      for (int i = 0; i < 8; ++i) { float f = ubf(v[i]); s += f * f; }
    }
    rcpA[(size_t)(seq0 + seq) * L + row] = (s > 0.f) ? rsqrtf(s) : 0.f;
  }

  // ---- conv MFMA ----
  f32x4 acc[2][MT][4];
#pragma unroll
  for (int seq = 0; seq < 2; ++seq)
#pragma unroll
    for (int mt = 0; mt < MT; ++mt)
#pragma unroll
      for (int n = 0; n < 4; ++n)
#pragma unroll
        for (int r = 0; r < 4; ++r) acc[seq][mt][n][r] = 0.f;

  const s16x8* fBv = (const s16x8*)fB;
  for (int kstep = 0; kstep < 10; ++kstep) {
#pragma unroll
    for (int tap = 0; tap < 3; ++tap) {
      s16x8 b[4];
#pragma unroll
      for (int n = 0; n < 4; ++n)
        b[n] = fBv[((size_t)((tap * 10 + kstep) * 16 + (wv * 4 + n))) * 64 + lane];
      s16x8 a[2][MT];
#pragma unroll
      for (int seq = 0; seq < 2; ++seq)
#pragma unroll
        for (int mt = 0; mt < MT; ++mt) {
          int row = mt * 16 + lr + tap;
          int flat = seq * R320 + row * 320 + kstep * 32 + lh * 8;
          int swz = flat ^ ((row & 7) << 3);
          a[seq][mt] = *(const s16x8*)(xs + swz);
        }
#pragma unroll
      for (int seq = 0; seq < 2; ++seq)
#pragma unroll
        for (int mt = 0; mt < MT; ++mt)
#pragma unroll
          for (int n = 0; n < 4; ++n)
            acc[seq][mt][n] = __builtin_amdgcn_mfma_f32_16x16x32_bf16(
                a[seq][mt], b[n], acc[seq][mt][n], 0, 0, 0);
    }
  }
  __syncthreads();   // all xs readers (blobA, norms, MFMA A-frags) done

  // ---- write conv output back into xs as bf16 (rows j<L, cols<256).
  //      rows >= L keep their staged zeros; cols 256.. never read by blobC (KS=8).
#pragma unroll
  for (int seq = 0; seq < 2; ++seq)
#pragma unroll
    for (int mt = 0; mt < MT; ++mt)
#pragma unroll
      for (int n = 0; n < 4; ++n)
#pragma unroll
        for (int r = 0; r < 4; ++r) {
          int j = mt * 16 + lh * 4 + r;
          if (j < L) {
            int f = wv * 64 + n * 16 + lr;
            int flat = seq * R320 + j * 320 + f;
            xs[flat ^ ((j & 7) << 3)] = bf16rne(acc[seq][mt][n][r]);
          }
        }
  __syncthreads();

  // ---- pack blobC (phase-1 sim fragments, KS=8) ----
  {
    constexpr int T = 2 * 8 * MT;
    for (int t = wv; t < T; t += 4) {
      int seq = t / (8 * MT);
      int rem = t - seq * (8 * MT);
      int kstep = rem / MT, tile = rem - kstep * MT;
      int row = tile * 16 + lr;
      int flat = seq * R320 + row * 320 + kstep * 32 + lh * 8;
      s16x8 v = *(const s16x8*)(xs + (flat ^ ((row & 7) << 3)));
      *(s16x8*)(blobC + ((((size_t)(seq0 + seq) * 8 + kstep) * MT + tile) * 64 + lane) * 8) = v;
    }
  }
  // ---- phase-1 norms (cols 0..255) ----
  if (tid < 2 * L) {
    int seq = tid / L, row = tid - seq * L;
    float s = 0.f;
    for (int c = 0; c < 32; ++c) {
      int flat = seq * R320 + row * 320 + c * 8;
      s16x8 v = *(const s16x8*)(xs + (flat ^ ((row & 7) << 3)));
#pragma unroll
      for (int i = 0; i < 8; ++i) { float f = ubf(v[i]); s += f * f; }
    }
    rcpC[(size_t)(seq0 + seq) * L + row] = (s > 0.f) ? rsqrtf(s) : 0.f;
  }
}

// One block per (b,s): MFMA sims from pre-packed fragment blobs (register-direct),
// then duplicate-safe top-5 pooling + sigmoid + mean.
__global__ __launch_bounds__(256, 6) void k_sim(const float* __restrict__ oneh,
                                                const ushort* __restrict__ qeb,
                                                const ushort* __restrict__ seb,
                                                const ushort* __restrict__ qcb,
                                                const ushort* __restrict__ scb,
                                                const float* __restrict__ rq0,
                                                const float* __restrict__ rs0,
                                                const float* __restrict__ rq1,
                                                const float* __restrict__ rs1,
                                                const float* __restrict__ lin_w,
                                                const float* __restrict__ lin_b,
                                                float* __restrict__ out) {
  const int bs = blockIdx.x;
  const int b = bs >> 5;
  const int tid = threadIdx.x;
  const int wv = tid >> 6, lane = tid & 63;
  const int lr = lane & 15, lh = lane >> 4;

  __shared__ float simb[2][30][49];
  __shared__ float ohl[30 * 41];
  __shared__ float rQ[2][30], rS[2][40];
  __shared__ float feats[30][6];
  __shared__ float lo[30];

  if (tid < 30) rQ[0][tid] = rq0[b * 30 + tid];
  else if (tid < 60) rQ[1][tid - 30] = rq1[b * 30 + (tid - 30)];
  else if (tid < 100) rS[0][tid - 60] = rs0[(size_t)bs * 40 + (tid - 60)];
  else if (tid < 140) rS[1][tid - 100] = rs1[(size_t)bs * 40 + (tid - 100)];
  {
    const float* og = oneh + (size_t)bs * 1200;
    for (int i = tid; i < 1200; i += 256) {
      int q = i / 40, l = i - q * 40;
      ohl[q * 41 + l] = og[i];
    }
  }
  __syncthreads();

  // 6 wave-tasks: (ph, nt); fragments loaded straight from global (coalesced 1KB/wave)
  for (int task = wv; task < 6; task += 4) {
    int ph = task / 3, nt = task - ph * 3;
    int KS = ph ? 8 : 10;
    const ushort* Ab = ph ? (qcb + (size_t)b * 8 * 2 * 512) : (qeb + (size_t)b * 10 * 2 * 512);
    const ushort* Bb = ph ? (scb + (size_t)bs * 8 * 3 * 512) : (seb + (size_t)bs * 10 * 3 * 512);
    f32x4 acc0 = {0.f, 0.f, 0.f, 0.f};
    f32x4 acc1 = {0.f, 0.f, 0.f, 0.f};
    for (int k = 0; k < KS; ++k) {
      s16x8 bf = *(const s16x8*)(Bb + ((size_t)(k * 3 + nt) * 64 + lane) * 8);
      s16x8 a0 = *(const s16x8*)(Ab + ((size_t)(k * 2 + 0) * 64 + lane) * 8);
      s16x8 a1 = *(const s16x8*)(Ab + ((size_t)(k * 2 + 1) * 64 + lane) * 8);
      acc0 = __builtin_amdgcn_mfma_f32_16x16x32_bf16(a0, bf, acc0, 0, 0, 0);
      acc1 = __builtin_amdgcn_mfma_f32_16x16x32_bf16(a1, bf, acc1, 0, 0, 0);
    }
    int l = nt * 16 + lr;
    if (l < 40) {
#pragma unroll
      for (int r = 0; r < 4; ++r) {
        int q0 = lh * 4 + r;                       // < 16
        simb[ph][q0][l] = acc0[r] * rQ[ph][q0] * rS[ph][l];
        int q1 = 16 + lh * 4 + r;
        if (q1 < 30) simb[ph][q1][l] = acc1[r] * rQ[ph][q1] * rS[ph][l];
      }
    }
  }
  __syncthreads();

  // duplicate-safe top-5 pooling on 90 threads
  if (tid < 90) {
    const int m = tid / 30, q = tid - m * 30;
    const float* row = (m == 0) ? &simb[0][q][0] : (m == 1) ? &simb[1][q][0] : (ohl + q * 41);
    float thr = 3.4e38f;
    int got = 0;
    float sum = 0.f, maxv = 0.f;
    while (got < 5) {
      float mx = -3.4e38f;
      int c = 0;
      for (int l = 0; l < 40; ++l) {
        float v = row[l];
        if (v < thr) {
          if (v > mx) { mx = v; c = 1; }
          else if (v == mx) { c++; }
        }
      }
      if (c == 0) break;  // safety: never hang
      if (got == 0) maxv = mx;
      int take = (c < 5 - got) ? c : (5 - got);
      sum += mx * (float)take;
      got += take;
      thr = mx;
    }
    feats[q][m * 2 + 0] = maxv;
    feats[q][m * 2 + 1] = sum * 0.2f;
  }
  __syncthreads();
  if (tid < 30) {
    float z = lin_b[0];
#pragma unroll
    for (int i = 0; i < 6; ++i) z += feats[tid][i] * lin_w[i];
    lo[tid] = 1.0f / (1.0f + expf(-z));
  }
  __syncthreads();
  if (tid == 0) {
    float sum = 0.f;
    for (int q = 0; q < 30; ++q) sum += lo[q];
    out[1 + bs] = sum * (1.0f / 30.0f);
  }
}

__global__ __launch_bounds__(256) void k_loss(const int* __restrict__ tsent,
                                              const int* __restrict__ tdoc,
                                              float* __restrict__ out) {
  __shared__ float red[256];
  __shared__ float sent_loss_sh;
  const int tid = threadIdx.x;
  float local = 0.f;
  for (int i = tid; i < 1024; i += 256) {
    float p = out[1 + i];
    float t = (float)tsent[i];
    float lp = fmaxf(logf(p), -100.f);
    float l1 = fmaxf(logf(1.f - p), -100.f);
    local += -(t * lp + (1.f - t) * l1);
  }
  red[tid] = local;
  __syncthreads();
  for (int off = 128; off > 0; off >>= 1) {
    if (tid < off) red[tid] += red[tid + off];
    __syncthreads();
  }
  if (tid == 0) sent_loss_sh = red[0] * (1.0f / 1024.0f);
  __syncthreads();
  float dterm = 0.f;
  if (tid < 32) {
    float mx = out[1 + tid * 32];
    for (int s2 = 1; s2 < 32; ++s2) mx = fmaxf(mx, out[1 + tid * 32 + s2]);
    out[1025 + tid] = mx;
    float t = (float)tdoc[tid];
    float lp = fmaxf(logf(mx), -100.f);
    float l1 = fmaxf(logf(1.f - mx), -100.f);
    dterm = -(t * lp + (1.f - t) * l1);
  }
  red[tid] = dterm;
  __syncthreads();
  for (int off = 128; off > 0; off >>= 1) {
    if (tid < off) red[tid] += red[tid + off];
    __syncthreads();
  }
  if (tid == 0) out[0] = 0.5f * (sent_loss_sh + red[0] * (1.0f / 32.0f));
}

extern "C" void kernel_launch(void* const* d_in, const int* in_sizes, int n_in,
                              void* d_out, int out_size, void* d_ws, size_t ws_size,
                              hipStream_t stream) {
  const int*   question     = (const int*)d_in[0];
  const int*   sentences    = (const int*)d_in[1];
  const int*   target_sents = (const int*)d_in[2];
  const int*   target_docs  = (const int*)d_in[3];
  const float* oneh         = (const float*)d_in[4];
  const float* embeds       = (const float*)d_in[5];
  const float* filters      = (const float*)d_in[6];
  const float* lin_w        = (const float*)d_in[7];
  const float* lin_b        = (const float*)d_in[8];
  float* out = (float*)d_out;

  // workspace layout (bytes):
  ushort* fB  = (ushort*)d_ws;             // 480*64*8        = 245,760 ush (491.5 KB)
  ushort* seb = fB  + 245760;              // 1024*10*3*512   = 15,728,640 ush (30 MB)
  ushort* scb = seb + 15728640;            // 1024*8*3*512    = 12,582,912 ush (24 MB)
  ushort* qeb = scb + 12582912;            // 32*10*2*512     = 327,680 ush
  ushort* qcb = qeb + 327680;              // 32*8*2*512      = 262,144 ush
  float*  rs0 = (float*)(qcb + 262144);    // 1024*40
  float*  rs1 = rs0 + 40960;               // 1024*40
  float*  rq0 = rs1 + 40960;               // 32*30
  float*  rq1 = rq0 + 960;                 // 32*30

  k_prepB<<<480, 64, 0, stream>>>(filters, fB);
  k_conv_mfma<40, 3, 50><<<512, 256, 0, stream>>>(sentences, embeds, fB, seb, scb, rs0, rs1);
  k_conv_mfma<30, 2, 34><<<16, 256, 0, stream>>>(question, embeds, fB, qeb, qcb, rq0, rq1);
  k_sim<<<1024, 256, 0, stream>>>(oneh, qeb, seb, qcb, scb, rq0, rs0, rq1, rs1,
                                  lin_w, lin_b, out);
  k_loss<<<1, 256, 0, stream>>>(target_sents, target_docs, out);
}

// Round 6
// 98.616 us; speedup vs baseline: 8.4461x; 1.9227x over previous
//
#include <hip/hip_runtime.h>
#include <math.h>

// B=32, S=32, LQ=30, LS=40, D=300, F=256, FS=3, K=5
// out layout: [0]=total_loss, [1..1024]=sent_output(B,S), [1025..1056]=doc_em(B)

typedef __attribute__((ext_vector_type(4))) float f32x4;
typedef __attribute__((ext_vector_type(8))) short s16x8;

__device__ inline ushort bf16rne(float f) {
  unsigned u = __float_as_uint(f);
  u += 0x7fff + ((u >> 16) & 1);
  return (ushort)(u >> 16);
}
__device__ inline uint pack2(float a, float b) {
  return (uint)bf16rne(a) | ((uint)bf16rne(b) << 16);
}
__device__ inline float ubf(short h) { return __uint_as_float(((uint)(ushort)h) << 16); }

// Pack filters into MFMA B-fragment-major layout:
// fB[((tap*10+kstep)*16 + nt)*64 + lane][8] ; B[k][col]: col=lane&15, k=(lane>>4)*8+i
__global__ __launch_bounds__(64) void k_prepB(const float* __restrict__ filters,
                                              ushort* __restrict__ fB) {
  const int bid = blockIdx.x;            // (tap*10+kstep)*16 + nt, 480 total
  const int lane = threadIdx.x;
  const int nt = bid & 15;
  const int tk = bid >> 4;
  const int tap = tk / 10, kstep = tk - tap * 10;
  const int f = nt * 16 + (lane & 15);
  const int kb = kstep * 32 + (lane >> 4) * 8;
  uint p[4];
#pragma unroll
  for (int h = 0; h < 4; ++h) {
    int d0 = kb + h * 2, d1 = kb + h * 2 + 1;
    float v0 = (d0 < 300) ? filters[(size_t)f * 900 + tap * 300 + d0] : 0.f;
    float v1 = (d1 < 300) ? filters[(size_t)f * 900 + tap * 300 + d1] : 0.f;
    p[h] = (uint)bf16rne(v0) | ((uint)bf16rne(v1) << 16);
  }
  uint4* dst = (uint4*)(fB + ((size_t)bid * 64 + lane) * 8);
  *dst = make_uint4(p[0], p[1], p[2], p[3]);
}

// MFMA conv, ONE sequence per block, 4 waves (wave w owns filter cols w*64..).
// Emits conv output as sim fragments plus:
//  - blobA: embeds bf16 fragments   [kstep<10][tile<MT][lane][8]  (sim phase 0)
//  - blobC: conv-out bf16 fragments [kstep< 8][tile<MT][lane][8]  (sim phase 1)
//  - rcpA/rcpC: per-row 1/||x|| from the same bf16 data
template<int L, int MT, int ROWS_ST>
__global__ __launch_bounds__(256) void k_conv_mfma(const int* __restrict__ tokens,
                                                   const float* __restrict__ embeds,
                                                   const ushort* __restrict__ fB,
                                                   ushort* __restrict__ blobA,
                                                   ushort* __restrict__ blobC,
                                                   float* __restrict__ rcpA,
                                                   float* __restrict__ rcpC) {
  constexpr int R320 = ROWS_ST * 320;
  __shared__ __align__(16) ushort xs[R320];
  __shared__ int tok[64];
  const int tid = threadIdx.x;
  const int seq = blockIdx.x;

  if (tid < L) tok[tid] = tokens[(size_t)seq * L + tid];
  __syncthreads();

  // stage embeds rows as bf16, swizzled (flat ^ (row&7)<<3), zero-padded.
  // item granularity: float4 -> uint2 (8B LDS write; 4-aligned chunk, XOR granule 8 -> safe)
  for (int idx = tid; idx < ROWS_ST * 80; idx += 256) {
    int row = idx / 80;
    int s = idx - row * 80;
    int d = s * 4;
    float4 v = make_float4(0.f, 0.f, 0.f, 0.f);
    if (row < L && d < 300) v = *(const float4*)(embeds + (size_t)tok[row] * 300 + d);
    int flat = row * 320 + d;
    int swz = flat ^ ((row & 7) << 3);
    *(uint2*)(xs + swz) = make_uint2(pack2(v.x, v.y), pack2(v.z, v.w));
  }
  __syncthreads();

  const int wv = tid >> 6, lane = tid & 63;
  const int lr = lane & 15, lh = lane >> 4;

  // ---- pack blobA (phase-0 sim fragments) ----
  for (int t = wv; t < 10 * MT; t += 4) {
    int kstep = t / MT, tile = t - kstep * MT;
    int row = tile * 16 + lr;
    int flat = row * 320 + kstep * 32 + lh * 8;
    s16x8 v = *(const s16x8*)(xs + (flat ^ ((row & 7) << 3)));
    *(s16x8*)(blobA + ((((size_t)seq * 10 + kstep) * MT + tile) * 64 + lane) * 8) = v;
  }
  // ---- phase-0 norms ----
  if (tid < L) {
    int row = tid;
    float s = 0.f;
    for (int c = 0; c < 40; ++c) {
      int flat = row * 320 + c * 8;
      s16x8 v = *(const s16x8*)(xs + (flat ^ ((row & 7) << 3)));
#pragma unroll
      for (int i = 0; i < 8; ++i) { float f = ubf(v[i]); s += f * f; }
    }
    rcpA[(size_t)seq * L + row] = (s > 0.f) ? rsqrtf(s) : 0.f;
  }

  // ---- conv MFMA ----
  f32x4 acc[MT][4];
#pragma unroll
  for (int mt = 0; mt < MT; ++mt)
#pragma unroll
    for (int n = 0; n < 4; ++n)
#pragma unroll
      for (int r = 0; r < 4; ++r) acc[mt][n][r] = 0.f;

  const s16x8* fBv = (const s16x8*)fB;
  for (int kstep = 0; kstep < 10; ++kstep) {
#pragma unroll
    for (int tap = 0; tap < 3; ++tap) {
      s16x8 b[4];
#pragma unroll
      for (int n = 0; n < 4; ++n)
        b[n] = fBv[((size_t)((tap * 10 + kstep) * 16 + (wv * 4 + n))) * 64 + lane];
#pragma unroll
      for (int mt = 0; mt < MT; ++mt) {
        int row = mt * 16 + lr + tap;
        int flat = row * 320 + kstep * 32 + lh * 8;
        s16x8 a = *(const s16x8*)(xs + (flat ^ ((row & 7) << 3)));
#pragma unroll
        for (int n = 0; n < 4; ++n)
          acc[mt][n] = __builtin_amdgcn_mfma_f32_16x16x32_bf16(a, b[n], acc[mt][n], 0, 0, 0);
      }
    }
  }
  __syncthreads();   // all xs readers (blobA, norms, MFMA A-frags) done

  // ---- write conv output back into xs as bf16 (rows j<L, cols<256).
  //      rows >= L keep staged zeros; cols 256.. never read by blobC (KS=8).
#pragma unroll
  for (int mt = 0; mt < MT; ++mt)
#pragma unroll
    for (int n = 0; n < 4; ++n)
#pragma unroll
      for (int r = 0; r < 4; ++r) {
        int j = mt * 16 + lh * 4 + r;
        if (j < L) {
          int f = wv * 64 + n * 16 + lr;
          int flat = j * 320 + f;
          xs[flat ^ ((j & 7) << 3)] = bf16rne(acc[mt][n][r]);
        }
      }
  __syncthreads();

  // ---- pack blobC (phase-1 sim fragments, KS=8) ----
  for (int t = wv; t < 8 * MT; t += 4) {
    int kstep = t / MT, tile = t - kstep * MT;
    int row = tile * 16 + lr;
    int flat = row * 320 + kstep * 32 + lh * 8;
    s16x8 v = *(const s16x8*)(xs + (flat ^ ((row & 7) << 3)));
    *(s16x8*)(blobC + ((((size_t)seq * 8 + kstep) * MT + tile) * 64 + lane) * 8) = v;
  }
  // ---- phase-1 norms (cols 0..255) ----
  if (tid < L) {
    int row = tid;
    float s = 0.f;
    for (int c = 0; c < 32; ++c) {
      int flat = row * 320 + c * 8;
      s16x8 v = *(const s16x8*)(xs + (flat ^ ((row & 7) << 3)));
#pragma unroll
      for (int i = 0; i < 8; ++i) { float f = ubf(v[i]); s += f * f; }
    }
    rcpC[(size_t)seq * L + row] = (s > 0.f) ? rsqrtf(s) : 0.f;
  }
}

// One block per (b,s): MFMA sims from pre-packed fragment blobs (register-direct),
// then duplicate-safe top-5 pooling + sigmoid + mean.
__global__ __launch_bounds__(256, 6) void k_sim(const float* __restrict__ oneh,
                                                const ushort* __restrict__ qeb,
                                                const ushort* __restrict__ seb,
                                                const ushort* __restrict__ qcb,
                                                const ushort* __restrict__ scb,
                                                const float* __restrict__ rq0,
                                                const float* __restrict__ rs0,
                                                const float* __restrict__ rq1,
                                                const float* __restrict__ rs1,
                                                const float* __restrict__ lin_w,
                                                const float* __restrict__ lin_b,
                                                float* __restrict__ out) {
  const int bs = blockIdx.x;
  const int b = bs >> 5;
  const int tid = threadIdx.x;
  const int wv = tid >> 6, lane = tid & 63;
  const int lr = lane & 15, lh = lane >> 4;

  __shared__ float simb[2][30][49];
  __shared__ float ohl[30 * 41];
  __shared__ float rQ[2][30], rS[2][40];
  __shared__ float feats[30][6];
  __shared__ float lo[30];

  if (tid < 30) rQ[0][tid] = rq0[b * 30 + tid];
  else if (tid < 60) rQ[1][tid - 30] = rq1[b * 30 + (tid - 30)];
  else if (tid < 100) rS[0][tid - 60] = rs0[(size_t)bs * 40 + (tid - 60)];
  else if (tid < 140) rS[1][tid - 100] = rs1[(size_t)bs * 40 + (tid - 100)];
  {
    const float* og = oneh + (size_t)bs * 1200;
    for (int i = tid; i < 1200; i += 256) {
      int q = i / 40, l = i - q * 40;
      ohl[q * 41 + l] = og[i];
    }
  }
  __syncthreads();

  // 6 wave-tasks: (ph, nt); fragments loaded straight from global (coalesced 1KB/wave)
  for (int task = wv; task < 6; task += 4) {
    int ph = task / 3, nt = task - ph * 3;
    int KS = ph ? 8 : 10;
    const ushort* Ab = ph ? (qcb + (size_t)b * 8 * 2 * 512) : (qeb + (size_t)b * 10 * 2 * 512);
    const ushort* Bb = ph ? (scb + (size_t)bs * 8 * 3 * 512) : (seb + (size_t)bs * 10 * 3 * 512);
    f32x4 acc0 = {0.f, 0.f, 0.f, 0.f};
    f32x4 acc1 = {0.f, 0.f, 0.f, 0.f};
    for (int k = 0; k < KS; ++k) {
      s16x8 bf = *(const s16x8*)(Bb + ((size_t)(k * 3 + nt) * 64 + lane) * 8);
      s16x8 a0 = *(const s16x8*)(Ab + ((size_t)(k * 2 + 0) * 64 + lane) * 8);
      s16x8 a1 = *(const s16x8*)(Ab + ((size_t)(k * 2 + 1) * 64 + lane) * 8);
      acc0 = __builtin_amdgcn_mfma_f32_16x16x32_bf16(a0, bf, acc0, 0, 0, 0);
      acc1 = __builtin_amdgcn_mfma_f32_16x16x32_bf16(a1, bf, acc1, 0, 0, 0);
    }
    int l = nt * 16 + lr;
    if (l < 40) {
#pragma unroll
      for (int r = 0; r < 4; ++r) {
        int q0 = lh * 4 + r;                       // < 16
        simb[ph][q0][l] = acc0[r] * rQ[ph][q0] * rS[ph][l];
        int q1 = 16 + lh * 4 + r;
        if (q1 < 30) simb[ph][q1][l] = acc1[r] * rQ[ph][q1] * rS[ph][l];
      }
    }
  }
  __syncthreads();

  // duplicate-safe top-5 pooling on 90 threads
  if (tid < 90) {
    const int m = tid / 30, q = tid - m * 30;
    const float* row = (m == 0) ? &simb[0][q][0] : (m == 1) ? &simb[1][q][0] : (ohl + q * 41);
    float thr = 3.4e38f;
    int got = 0;
    float sum = 0.f, maxv = 0.f;
    while (got < 5) {
      float mx = -3.4e38f;
      int c = 0;
      for (int l = 0; l < 40; ++l) {
        float v = row[l];
        if (v < thr) {
          if (v > mx) { mx = v; c = 1; }
          else if (v == mx) { c++; }
        }
      }
      if (c == 0) break;  // safety: never hang
      if (got == 0) maxv = mx;
      int take = (c < 5 - got) ? c : (5 - got);
      sum += mx * (float)take;
      got += take;
      thr = mx;
    }
    feats[q][m * 2 + 0] = maxv;
    feats[q][m * 2 + 1] = sum * 0.2f;
  }
  __syncthreads();
  if (tid < 30) {
    float z = lin_b[0];
#pragma unroll
    for (int i = 0; i < 6; ++i) z += feats[tid][i] * lin_w[i];
    lo[tid] = 1.0f / (1.0f + expf(-z));
  }
  __syncthreads();
  if (tid == 0) {
    float sum = 0.f;
    for (int q = 0; q < 30; ++q) sum += lo[q];
    out[1 + bs] = sum * (1.0f / 30.0f);
  }
}

__global__ __launch_bounds__(256) void k_loss(const int* __restrict__ tsent,
                                              const int* __restrict__ tdoc,
                                              float* __restrict__ out) {
  __shared__ float red[256];
  __shared__ float sent_loss_sh;
  const int tid = threadIdx.x;
  float local = 0.f;
  for (int i = tid; i < 1024; i += 256) {
    float p = out[1 + i];
    float t = (float)tsent[i];
    float lp = fmaxf(logf(p), -100.f);
    float l1 = fmaxf(logf(1.f - p), -100.f);
    local += -(t * lp + (1.f - t) * l1);
  }
  red[tid] = local;
  __syncthreads();
  for (int off = 128; off > 0; off >>= 1) {
    if (tid < off) red[tid] += red[tid + off];
    __syncthreads();
  }
  if (tid == 0) sent_loss_sh = red[0] * (1.0f / 1024.0f);
  __syncthreads();
  float dterm = 0.f;
  if (tid < 32) {
    float mx = out[1 + tid * 32];
    for (int s2 = 1; s2 < 32; ++s2) mx = fmaxf(mx, out[1 + tid * 32 + s2]);
    out[1025 + tid] = mx;
    float t = (float)tdoc[tid];
    float lp = fmaxf(logf(mx), -100.f);
    float l1 = fmaxf(logf(1.f - mx), -100.f);
    dterm = -(t * lp + (1.f - t) * l1);
  }
  red[tid] = dterm;
  __syncthreads();
  for (int off = 128; off > 0; off >>= 1) {
    if (tid < off) red[tid] += red[tid + off];
    __syncthreads();
  }
  if (tid == 0) out[0] = 0.5f * (sent_loss_sh + red[0] * (1.0f / 32.0f));
}

extern "C" void kernel_launch(void* const* d_in, const int* in_sizes, int n_in,
                              void* d_out, int out_size, void* d_ws, size_t ws_size,
                              hipStream_t stream) {
  const int*   question     = (const int*)d_in[0];
  const int*   sentences    = (const int*)d_in[1];
  const int*   target_sents = (const int*)d_in[2];
  const int*   target_docs  = (const int*)d_in[3];
  const float* oneh         = (const float*)d_in[4];
  const float* embeds       = (const float*)d_in[5];
  const float* filters      = (const float*)d_in[6];
  const float* lin_w        = (const float*)d_in[7];
  const float* lin_b        = (const float*)d_in[8];
  float* out = (float*)d_out;

  // workspace layout:
  ushort* fB  = (ushort*)d_ws;             // 480*64*8        = 245,760 ush (491.5 KB)
  ushort* seb = fB  + 245760;              // 1024*10*3*512   = 15,728,640 ush (30 MB)
  ushort* scb = seb + 15728640;            // 1024*8*3*512    = 12,582,912 ush (24 MB)
  ushort* qeb = scb + 12582912;            // 32*10*2*512     = 327,680 ush
  ushort* qcb = qeb + 327680;              // 32*8*2*512      = 262,144 ush
  float*  rs0 = (float*)(qcb + 262144);    // 1024*40
  float*  rs1 = rs0 + 40960;               // 1024*40
  float*  rq0 = rs1 + 40960;               // 32*30
  float*  rq1 = rq0 + 960;                 // 32*30

  k_prepB<<<480, 64, 0, stream>>>(filters, fB);
  k_conv_mfma<40, 3, 50><<<1024, 256, 0, stream>>>(sentences, embeds, fB, seb, scb, rs0, rs1);
  k_conv_mfma<30, 2, 34><<<32, 256, 0, stream>>>(question, embeds, fB, qeb, qcb, rq0, rq1);
  k_sim<<<1024, 256, 0, stream>>>(oneh, qeb, seb, qcb, scb, rq0, rs0, rq1, rs1,
                                  lin_w, lin_b, out);
  k_loss<<<1, 256, 0, stream>>>(target_sents, target_docs, out);
}